// Round 8
// baseline (5390.277 us; speedup 1.0000x reference)
//
#include <hip/hip_runtime.h>

#define BATCH 64
#define SEQ   4096
#define ISZ   64
#define RSZ   128

typedef float f32x4_t __attribute__((ext_vector_type(4)));
typedef float f32x2_t __attribute__((ext_vector_type(2)));

__device__ __forceinline__ float fast_tanh(float x) {
    float e = __expf(2.0f * x);
    return 1.0f - 2.0f / (e + 1.0f);
}

// ---------------------------------------------------------------------------
// Kernel 1: projection. out[row][r] = tanh(sum_j x[row][j] * w_in[r][j])
// ---------------------------------------------------------------------------
__global__ __launch_bounds__(256) void proj_kernel(
        const float* __restrict__ x, const float* __restrict__ w_in,
        float* __restrict__ out) {
    __shared__ float wT[ISZ][RSZ];
    __shared__ float xs[32][ISZ];

    const int tid = threadIdx.x;

    for (int idx = tid; idx < RSZ * ISZ / 4; idx += 256) {
        const int r  = idx >> 4;
        const int j4 = (idx & 15) << 2;
        const float4 v = reinterpret_cast<const float4*>(w_in)[idx];
        wT[j4 + 0][r] = v.x; wT[j4 + 1][r] = v.y;
        wT[j4 + 2][r] = v.z; wT[j4 + 3][r] = v.w;
    }
    const long row0 = (long)blockIdx.x * 32;
    #pragma unroll
    for (int q = 0; q < 2; ++q) {
        const int idx = tid + q * 256;
        reinterpret_cast<float4*>(&xs[0][0])[idx] =
            reinterpret_cast<const float4*>(x + row0 * ISZ)[idx];
    }
    __syncthreads();

    const int rq = tid & 31;
    const int rp = tid >> 5;
    const int r0 = rq << 2;
    const int ra = rp << 2;

    float acc[4][4] = {};
    #pragma unroll
    for (int j4 = 0; j4 < ISZ; j4 += 4) {
        float4 xv[4];
        #pragma unroll
        for (int m = 0; m < 4; ++m)
            xv[m] = *reinterpret_cast<const float4*>(&xs[ra + m][j4]);
        #pragma unroll
        for (int k = 0; k < 4; ++k) {
            const float4 w = *reinterpret_cast<const float4*>(&wT[j4 + k][r0]);
            #pragma unroll
            for (int m = 0; m < 4; ++m) {
                const float xm = k == 0 ? xv[m].x : k == 1 ? xv[m].y
                               : k == 2 ? xv[m].z : xv[m].w;
                acc[m][0] += xm * w.x; acc[m][1] += xm * w.y;
                acc[m][2] += xm * w.z; acc[m][3] += xm * w.w;
            }
        }
    }
    #pragma unroll
    for (int m = 0; m < 4; ++m) {
        float4 o;
        o.x = fast_tanh(acc[m][0]); o.y = fast_tanh(acc[m][1]);
        o.z = fast_tanh(acc[m][2]); o.w = fast_tanh(acc[m][3]);
        *reinterpret_cast<float4*>(&out[(row0 + ra + m) * RSZ + r0]) = o;
    }
}

// ---------------------------------------------------------------------------
// Kernel 2: sequential scan — ONE WAVE PER BATCH, ZERO BARRIERS.
// 64 blocks x 64 threads. Lane l owns outputs {2l, 2l+1}: full 128-deep dots
// with W rows in ~256 VGPRs (launch_bounds(64,1) -> 512-VGPR budget, 1 wave/
// SIMD so occupancy is irrelevant). h lives in a 16-slot LDS ring; exchange
// is intra-wave: ds_write_b64 own pair -> s_waitcnt lgkmcnt(0) (wave-internal
// ordering, no s_barrier, no cross-wave skew) -> 32 broadcast ds_read_b128.
// 16-step unrolled loop => all slot indices compile-time (imm-offset LDS).
// Outputs flushed from the same ring every 8 steps via coalesced NT stores
// (round-6 lesson: keep per-step global stores out of the vmcnt FIFO);
// u prefetched 4 steps ahead as coalesced f32x2.
// STEP(S): reads slot S&15 (state h_t), writes slot (S+1)&15 (h_{t+1}).
// FLUSH(P): rows t0+P..t0+P+7 from slots (P+1..P+8)&15 — disjoint from the
// slots the next 8 STEPs write, so no wait needed beyond lgkm ordering.
// ---------------------------------------------------------------------------
__global__ __launch_bounds__(64, 1) void scan_kernel(
        const float* __restrict__ w_res, float* __restrict__ io) {
    __shared__ float ring[16 * 128];     // 8 KB, slot = step & 15

    const int lane = threadIdx.x;        // 0..63, one wave
    const int r0   = lane * 2;

    // W_res rows r0, r0+1 fully in registers (256 floats)
    f32x2_t w0[64], w1[64];
    #pragma unroll
    for (int k = 0; k < 128; k += 4) {
        const f32x4_t v0 = *reinterpret_cast<const f32x4_t*>(
            &w_res[r0 * RSZ + k]);
        const f32x4_t v1 = *reinterpret_cast<const f32x4_t*>(
            &w_res[(r0 + 1) * RSZ + k]);
        w0[k / 2] = v0.xy; w0[k / 2 + 1] = v0.zw;
        w1[k / 2] = v1.xy; w1[k / 2 + 1] = v1.zw;
    }

    float* const out = io + (long)blockIdx.x * (SEQ * RSZ);

    // h_0 = 0 in slot 0
    ring[lane] = 0.f;
    ring[64 + lane] = 0.f;

    // 4-deep u prefetch ring (coalesced f32x2 per lane)
    f32x2_t u[4];
    #pragma unroll
    for (int s = 0; s < 4; ++s)
        u[s] = *reinterpret_cast<const f32x2_t*>(&out[s * RSZ + r0]);
    f32x2_t hreg = {0.f, 0.f};

    asm volatile("s_waitcnt lgkmcnt(0)" ::: "memory");

    // nh = 0.5*h + 0.5*tanh(v) = fma(0.5,h,0.5) - 1/(exp2(2*log2e*v)+1)
    #define ACT(HH, VV)                                                       \
        (fmaf(0.5f, (HH), 0.5f) -                                             \
         __builtin_amdgcn_rcpf(                                               \
             __builtin_amdgcn_exp2f((VV) * 2.885390082f) + 1.0f))

    #define STEP(S)                                                           \
    {                                                                         \
        int tp = t0 + (S) + 4;                                                \
        if (tp > SEQ - 1) tp = SEQ - 1;                                       \
        const f32x2_t uc = u[(S) & 3];                                        \
        u[(S) & 3] = *reinterpret_cast<const f32x2_t*>(&out[tp * RSZ + r0]);  \
        const f32x4_t* hs = reinterpret_cast<const f32x4_t*>(                 \
            &ring[((S) & 15) * 128]);                                         \
        f32x2_t acc0a = {0.f, 0.f}, acc0b = {0.f, 0.f};                       \
        f32x2_t acc1a = {0.f, 0.f}, acc1b = {0.f, 0.f};                       \
        _Pragma("unroll")                                                     \
        for (int q = 0; q < 32; ++q) {                                        \
            const f32x4_t hv = hs[q];                                         \
            acc0a = __builtin_elementwise_fma(hv.xy, w0[2 * q + 0], acc0a);   \
            acc0b = __builtin_elementwise_fma(hv.zw, w0[2 * q + 1], acc0b);   \
            acc1a = __builtin_elementwise_fma(hv.xy, w1[2 * q + 0], acc1a);   \
            acc1b = __builtin_elementwise_fma(hv.zw, w1[2 * q + 1], acc1b);   \
        }                                                                     \
        const float a0 = (acc0a.x + acc0a.y) + (acc0b.x + acc0b.y);           \
        const float a1 = (acc1a.x + acc1a.y) + (acc1b.x + acc1b.y);           \
        f32x2_t nh;                                                           \
        nh.x = ACT(hreg.x, uc.x + a0);                                        \
        nh.y = ACT(hreg.y, uc.y + a1);                                        \
        hreg = nh;                                                            \
        *reinterpret_cast<f32x2_t*>(                                          \
            &ring[(((S) + 1) & 15) * 128 + r0]) = nh;                         \
        asm volatile("s_waitcnt lgkmcnt(0)" ::: "memory");                    \
    }

    #define FLUSH(P)                                                          \
    {                                                                         \
        _Pragma("unroll")                                                     \
        for (int q = 0; q < 4; ++q) {                                         \
            const int idxf = lane + 64 * q;                                   \
            const int j    = idxf >> 5;                                       \
            const int qi   = idxf & 31;                                       \
            const f32x4_t v = *reinterpret_cast<const f32x4_t*>(              \
                &ring[(((P) + j + 1) & 15) * 128 + qi * 4]);                  \
            __builtin_nontemporal_store(v, reinterpret_cast<f32x4_t*>(        \
                &out[(t0 + (P) + j) * RSZ + qi * 4]));                        \
        }                                                                     \
    }

    for (int t0 = 0; t0 < SEQ; t0 += 16) {
        STEP(0)  STEP(1)  STEP(2)  STEP(3)
        STEP(4)  STEP(5)  STEP(6)  STEP(7)
        FLUSH(0)
        STEP(8)  STEP(9)  STEP(10) STEP(11)
        STEP(12) STEP(13) STEP(14) STEP(15)
        FLUSH(8)
    }
    #undef STEP
    #undef FLUSH
    #undef ACT
}

extern "C" void kernel_launch(void* const* d_in, const int* in_sizes, int n_in,
                              void* d_out, int out_size, void* d_ws, size_t ws_size,
                              hipStream_t stream) {
    const float* x     = (const float*)d_in[0];
    const float* w_in  = (const float*)d_in[1];
    const float* w_res = (const float*)d_in[2];
    float* out = (float*)d_out;

    proj_kernel<<<(BATCH * SEQ) / 32, 256, 0, stream>>>(x, w_in, out);
    scan_kernel<<<BATCH, 64, 0, stream>>>(w_res, out);
}

// Round 10
// 1849.704 us; speedup vs baseline: 2.9141x; 2.9141x over previous
//
#include <hip/hip_runtime.h>

#define BATCH 64
#define SEQ   4096
#define ISZ   64
#define RSZ   128

typedef float  f32x4_t __attribute__((ext_vector_type(4)));
typedef float  f32x2_t __attribute__((ext_vector_type(2)));
typedef __fp16 f16x2_t __attribute__((ext_vector_type(2)));
typedef __fp16 f16x8_t __attribute__((ext_vector_type(8)));

__device__ __forceinline__ float fast_tanh(float x) {
    float e = __expf(2.0f * x);
    return 1.0f - 2.0f / (e + 1.0f);
}

__device__ __forceinline__ float dot2(f16x2_t a, f16x2_t b, float c) {
#if __has_builtin(__builtin_amdgcn_fdot2)
    return __builtin_amdgcn_fdot2(a, b, c, false);
#else
    return fmaf((float)a.x, (float)b.x, fmaf((float)a.y, (float)b.y, c));
#endif
}

// ---------------------------------------------------------------------------
// Kernel 1: projection. out[row][r] = tanh(sum_j x[row][j] * w_in[r][j])
// ---------------------------------------------------------------------------
__global__ __launch_bounds__(256) void proj_kernel(
        const float* __restrict__ x, const float* __restrict__ w_in,
        float* __restrict__ out) {
    __shared__ float wT[ISZ][RSZ];
    __shared__ float xs[32][ISZ];

    const int tid = threadIdx.x;

    for (int idx = tid; idx < RSZ * ISZ / 4; idx += 256) {
        const int r  = idx >> 4;
        const int j4 = (idx & 15) << 2;
        const float4 v = reinterpret_cast<const float4*>(w_in)[idx];
        wT[j4 + 0][r] = v.x; wT[j4 + 1][r] = v.y;
        wT[j4 + 2][r] = v.z; wT[j4 + 3][r] = v.w;
    }
    const long row0 = (long)blockIdx.x * 32;
    #pragma unroll
    for (int q = 0; q < 2; ++q) {
        const int idx = tid + q * 256;
        reinterpret_cast<float4*>(&xs[0][0])[idx] =
            reinterpret_cast<const float4*>(x + row0 * ISZ)[idx];
    }
    __syncthreads();

    const int rq = tid & 31;
    const int rp = tid >> 5;
    const int r0 = rq << 2;
    const int ra = rp << 2;

    float acc[4][4] = {};
    #pragma unroll
    for (int j4 = 0; j4 < ISZ; j4 += 4) {
        float4 xv[4];
        #pragma unroll
        for (int m = 0; m < 4; ++m)
            xv[m] = *reinterpret_cast<const float4*>(&xs[ra + m][j4]);
        #pragma unroll
        for (int k = 0; k < 4; ++k) {
            const float4 w = *reinterpret_cast<const float4*>(&wT[j4 + k][r0]);
            #pragma unroll
            for (int m = 0; m < 4; ++m) {
                const float xm = k == 0 ? xv[m].x : k == 1 ? xv[m].y
                               : k == 2 ? xv[m].z : xv[m].w;
                acc[m][0] += xm * w.x; acc[m][1] += xm * w.y;
                acc[m][2] += xm * w.z; acc[m][3] += xm * w.w;
            }
        }
    }
    #pragma unroll
    for (int m = 0; m < 4; ++m) {
        float4 o;
        o.x = fast_tanh(acc[m][0]); o.y = fast_tanh(acc[m][1]);
        o.z = fast_tanh(acc[m][2]); o.w = fast_tanh(acc[m][3]);
        *reinterpret_cast<float4*>(&out[(row0 + ra + m) * RSZ + r0]) = o;
    }
}

// ---------------------------------------------------------------------------
// Kernel 2: sequential scan — ONE WAVE PER BATCH, ZERO BARRIERS, f16 dots.
// 64 blocks x 64 threads. Lane l owns outputs {2l, 2l+1} with FULL 128-deep
// dots; W rows held as f16x2 (128 VGPR — fits, unlike round-8's 256-f32
// spill). Dot via v_dot2_f32_f16 (f32 accumulate): 128 ops for 256 MACs.
// h exchange is intra-wave lockstep: ds_write_b32 own f16x2 pair ->
// s_waitcnt lgkmcnt(0) -> 16 broadcast ds_read_b128. No s_barrier, no
// double-buffer needed (in-order DS pipe + wave lockstep).
// f16 precision: h,W quantization ~5e-4/step, ~10x recurrence amplification
// -> ~5e-3 absmax, well under the 1.89e-2 threshold. u stays f32.
// Outputs staged f32 in an 8-slot LDS ring, flushed every 8 steps with
// coalesced NT stores (keeps per-step stores out of the vmcnt FIFO);
// u prefetched 4 steps ahead as coalesced f32x2.
// ---------------------------------------------------------------------------
__global__ __launch_bounds__(64, 1) void scan_kernel(
        const float* __restrict__ w_res, float* __restrict__ io) {
    __shared__ f16x2_t hsh[64];          // full h as f16 pairs (256 B)
    __shared__ float   stage[8][RSZ];    // 4 KB output ring

    const int lane = threadIdx.x;        // 0..63, one wave
    const int o0   = lane * 2;           // owned outputs o0, o0+1

    // W rows o0, o0+1 -> f16x2 in 128 VGPRs
    f16x2_t wa[64], wb[64];
    #pragma unroll
    for (int k = 0; k < 128; k += 4) {
        const f32x4_t va = *reinterpret_cast<const f32x4_t*>(
            &w_res[o0 * RSZ + k]);
        const f32x4_t vb = *reinterpret_cast<const f32x4_t*>(
            &w_res[(o0 + 1) * RSZ + k]);
        wa[k / 2]     = __builtin_amdgcn_cvt_pkrtz(va.x, va.y);
        wa[k / 2 + 1] = __builtin_amdgcn_cvt_pkrtz(va.z, va.w);
        wb[k / 2]     = __builtin_amdgcn_cvt_pkrtz(vb.x, vb.y);
        wb[k / 2 + 1] = __builtin_amdgcn_cvt_pkrtz(vb.z, vb.w);
    }

    float* const out = io + (long)blockIdx.x * (SEQ * RSZ);

    hsh[lane] = __builtin_amdgcn_cvt_pkrtz(0.f, 0.f);   // h0 = 0

    // 4-deep u prefetch ring (coalesced f32x2 per lane)
    f32x2_t u[4];
    #pragma unroll
    for (int s = 0; s < 4; ++s)
        u[s] = *reinterpret_cast<const f32x2_t*>(&out[s * RSZ + o0]);
    f32x2_t hreg = {0.f, 0.f};

    asm volatile("s_waitcnt lgkmcnt(0)" ::: "memory");
    __builtin_amdgcn_sched_barrier(0);

    // nh = 0.5*h + 0.5*tanh(v) = fma(0.5,h,0.5) - 1/(exp2(2*log2e*v)+1)
    #define ACT(HH, VV)                                                       \
        (fmaf(0.5f, (HH), 0.5f) -                                             \
         __builtin_amdgcn_rcpf(                                               \
             __builtin_amdgcn_exp2f((VV) * 2.885390082f) + 1.0f))

    #define STEP(S)                                                           \
    {                                                                         \
        int tp = t0 + (S) + 4;                                                \
        if (tp > SEQ - 1) tp = SEQ - 1;                                       \
        const f32x2_t uc = u[(S) & 3];                                        \
        u[(S) & 3] = *reinterpret_cast<const f32x2_t*>(&out[tp * RSZ + o0]);  \
        const f16x8_t* hp = reinterpret_cast<const f16x8_t*>(&hsh[0]);        \
        float a0a = 0.f, a0b = 0.f, a1a = 0.f, a1b = 0.f;                     \
        _Pragma("unroll")                                                     \
        for (int q = 0; q < 16; ++q) {                                        \
            const f16x8_t hv = hp[q];                                         \
            const f16x2_t h0 = {hv[0], hv[1]}, h1 = {hv[2], hv[3]};           \
            const f16x2_t h2 = {hv[4], hv[5]}, h3 = {hv[6], hv[7]};           \
            a0a = dot2(h0, wa[4 * q + 0], a0a);                               \
            a0b = dot2(h1, wa[4 * q + 1], a0b);                               \
            a0a = dot2(h2, wa[4 * q + 2], a0a);                               \
            a0b = dot2(h3, wa[4 * q + 3], a0b);                               \
            a1a = dot2(h0, wb[4 * q + 0], a1a);                               \
            a1b = dot2(h1, wb[4 * q + 1], a1b);                               \
            a1a = dot2(h2, wb[4 * q + 2], a1a);                               \
            a1b = dot2(h3, wb[4 * q + 3], a1b);                               \
        }                                                                     \
        const float nh0 = ACT(hreg.x, uc.x + (a0a + a0b));                    \
        const float nh1 = ACT(hreg.y, uc.y + (a1a + a1b));                    \
        hreg.x = nh0; hreg.y = nh1;                                           \
        hsh[lane] = __builtin_amdgcn_cvt_pkrtz(nh0, nh1);                     \
        f32x2_t nv; nv.x = nh0; nv.y = nh1;                                   \
        *reinterpret_cast<f32x2_t*>(&stage[S][o0]) = nv;                      \
        asm volatile("s_waitcnt lgkmcnt(0)" ::: "memory");                    \
        __builtin_amdgcn_sched_barrier(0);                                    \
    }

    for (int t0 = 0; t0 < SEQ; t0 += 8) {
        STEP(0) STEP(1) STEP(2) STEP(3)
        STEP(4) STEP(5) STEP(6) STEP(7)
        // Flush 8 staged rows: coalesced LDS read + NT store, 4 per lane.
        #pragma unroll
        for (int q = 0; q < 4; ++q) {
            const int idxf = lane + 64 * q;         // 0..255
            const int j    = idxf >> 5;             // staged step 0..7
            const int qi   = (idxf & 31) * 4;       // element quad
            const f32x4_t v = *reinterpret_cast<const f32x4_t*>(
                &stage[j][qi]);
            __builtin_nontemporal_store(v, reinterpret_cast<f32x4_t*>(
                &out[(t0 + j) * RSZ + qi]));
        }
    }
    #undef STEP
    #undef ACT
}

extern "C" void kernel_launch(void* const* d_in, const int* in_sizes, int n_in,
                              void* d_out, int out_size, void* d_ws, size_t ws_size,
                              hipStream_t stream) {
    const float* x     = (const float*)d_in[0];
    const float* w_in  = (const float*)d_in[1];
    const float* w_res = (const float*)d_in[2];
    float* out = (float*)d_out;

    proj_kernel<<<(BATCH * SEQ) / 32, 256, 0, stream>>>(x, w_in, out);
    scan_kernel<<<BATCH, 64, 0, stream>>>(w_res, out);
}